// Round 15
// baseline (120.344 us; speedup 1.0000x reference)
//
#include <hip/hip_runtime.h>
#include <hip/hip_bf16.h>
#include <math.h>

#define B_    64
#define L_    2048
#define D_    512
#define EPS   6e-3f   // period-2 exit threshold; freeze error ~EPS/(1-rho^2)~8e-3

typedef _Float16 half2v __attribute__((ext_vector_type(2)));

// Packed f16 dot-2 with f32 accumulate (VOP3P v_dot2_f32_f16 via builtin).
__device__ inline float fdot2f(unsigned wu, unsigned hu, float acc) {
    return __builtin_amdgcn_fdot2(__builtin_bit_cast(half2v, wu),
                                  __builtin_bit_cast(half2v, hu), acc, false);
}

__device__ inline float fast_tanh(float x) {
    float e = __expf(2.0f * x);           // inf for large x is fine
    return 1.0f - 2.0f / (e + 1.0f);
}

// LDS-only barrier: waits this wave's LDS ops, then raw s_barrier.
// Does not drain vmcnt — output stores stay in flight across steps.
__device__ inline void lds_barrier() {
    asm volatile("s_waitcnt lgkmcnt(0)" ::: "memory");
    __builtin_amdgcn_s_barrier();
    __builtin_amdgcn_sched_barrier(0);
}

__device__ inline int clampc(int c) { return c < 0 ? 0 : (c > L_ ? L_ : c); }

__device__ inline unsigned packh(float lo, float hi) {
    half2v v; v[0] = (_Float16)lo; v[1] = (_Float16)hi;   // RNE casts
    return __builtin_bit_cast(unsigned, v);
}

// 64 blocks: TILED transpose W_hh -> WT8 packed f16 pairs only (u-GEMV moved
// into rnn). Layout: wt8[k8*512 + j*64 + lane] = pack(W_hh[lane*8+j][8k8..+8)).
// 8x8 grid of 64x64 tiles; reads 256B-contiguous, writes 128B-contiguous.
__global__ __launch_bounds__(512) void prep_kernel(
    const float* __restrict__ W_hh, uint4* __restrict__ wt8)
{
    const int T  = blockIdx.x;         // 0..63
    const int tid = threadIdx.x;
    const int gi = T >> 3, gj = T & 7; // tile (row-group, col-group)
    __shared__ unsigned st[64][32];    // 8 KB staged f16-pairs

    // read phase: thread reads 8 consecutive floats of one tile row
    const int r  = tid >> 3;           // 0..63 (row within tile)
    const int c8 = tid & 7;            // 0..7  (8-col group)
    const float* src = W_hh + (size_t)(64 * gi + r) * D_ + 64 * gj + c8 * 8;
    const float4 v0 = reinterpret_cast<const float4*>(src)[0];
    const float4 v1 = reinterpret_cast<const float4*>(src)[1];
    const int cw = ((c8 ^ (r & 7)) << 2);   // XOR swizzle, 4-aligned
    st[r][cw + 0] = packh(v0.x, v0.y);
    st[r][cw + 1] = packh(v0.z, v0.w);
    st[r][cw + 2] = packh(v1.x, v1.y);
    st[r][cw + 3] = packh(v1.z, v1.w);
    __syncthreads();

    // write phase: thread writes one uint4 of wt8, 128B-contiguous per (k8,j)
    const int k8l = tid >> 6;          // 0..7 (k8 within tile)
    const int j   = (tid >> 3) & 7;
    const int l8  = tid & 7;
    const int r2  = l8 * 8 + j;        // row within tile
    const int cr  = ((k8l ^ j) << 2);  // matches staging swizzle
    const uint4 o = *reinterpret_cast<const uint4*>(&st[r2][cr]);
    wt8[(size_t)(8 * gj + k8l) * D_ + j * 64 + 8 * gi + l8] = o;
}

#define REP48(M) M(0)M(1)M(2)M(3)M(4)M(5)M(6)M(7)M(8)M(9)M(10)M(11)M(12)M(13)\
M(14)M(15)M(16)M(17)M(18)M(19)M(20)M(21)M(22)M(23)M(24)M(25)M(26)M(27)M(28)\
M(29)M(30)M(31)M(32)M(33)M(34)M(35)M(36)M(37)M(38)M(39)M(40)M(41)M(42)M(43)\
M(44)M(45)M(46)M(47)

// 64 blocks x 512 threads. Fixed phase: coalesced in-block u-GEMV
// (u = x·W_ih^T + biases, 8-lane-group mapping, shfl-reduce) + W reg/LDS
// loads. Step loop: K-split across waves, h in registers (readlane
// broadcast), one lds_barrier/step, delayed period-2 exit.
__global__ __launch_bounds__(512, 2) void rnn_kernel(
    const int* __restrict__ counts, const float* __restrict__ x,
    const float* __restrict__ W_ih, const float* __restrict__ b_ih,
    const float* __restrict__ b_hh, const uint4* __restrict__ wt8,
    float* __restrict__ out, float* __restrict__ hA, float* __restrict__ hB,
    int* __restrict__ tstop)
{
    const int b    = blockIdx.x;
    const int tid  = threadIdx.x;
    const int w    = tid >> 6;     // wave 0..7
    const int lane = tid & 63;
    const int w8   = w * 8;        // first owned K-chunk
    const int count = clampc(counts[b]);

    __shared__ __align__(16) uint4 wl[2][8][512];        // 128 KB (j=6,7 tails)
    __shared__ __align__(16) _Float16 pb16[2][8][D_];    // 16 KB partials, dbuf
    __shared__ __align__(16) float xs[D_];               // 2 KB
    __shared__ float bs[D_];                             // 2 KB
    __shared__ float us[D_];                             // 2 KB
    __shared__ int flag[2];

    // ---- stage x and biases
    xs[tid] = x[b * D_ + tid];
    bs[tid] = b_ih[tid] + b_hh[tid];
    __syncthreads();

    // ---- u-GEMV: rows r = p*64 + w*8 + g; 8-lane group e covers cols.
    // Per W-load instr: 8 groups x 128B contiguous segments (coalesced).
    {
        const int g = lane >> 3, e = lane & 7;
        const float4* xsv = reinterpret_cast<const float4*>(xs);
        float sacc0 = 0.f, sacc1 = 0.f, sacc2 = 0.f, sacc3 = 0.f;
        float sacc4 = 0.f, sacc5 = 0.f, sacc6 = 0.f, sacc7 = 0.f;
        #pragma unroll
        for (int k = 0; k < 16; ++k) {
            const float4 xx = xsv[k * 8 + e];
            #define UROW(p) { \
                const float4 wv = reinterpret_cast<const float4*>( \
                    W_ih + (size_t)((p) * 64 + w * 8 + g) * D_)[k * 8 + e]; \
                sacc##p += wv.x*xx.x + wv.y*xx.y + wv.z*xx.z + wv.w*xx.w; }
            UROW(0) UROW(1) UROW(2) UROW(3) UROW(4) UROW(5) UROW(6) UROW(7)
            #undef UROW
        }
        #define URED(p) { \
            float s = sacc##p; \
            s += __shfl_xor(s, 1, 64); \
            s += __shfl_xor(s, 2, 64); \
            s += __shfl_xor(s, 4, 64); \
            if (e == 0) { const int r = (p) * 64 + w * 8 + g; us[r] = s + bs[r]; } }
        URED(0) URED(1) URED(2) URED(3) URED(4) URED(5) URED(6) URED(7)
        #undef URED
    }

    // ---- W loads j=0..5 into named regs (coalesced), j=6,7 into LDS.
    const uint4* wb = wt8 + (size_t)w8 * D_ + lane;
    #define WDEC(j) \
        uint4 w##j##_0 = wb[0*D_ + (j)*64]; uint4 w##j##_1 = wb[1*D_ + (j)*64]; \
        uint4 w##j##_2 = wb[2*D_ + (j)*64]; uint4 w##j##_3 = wb[3*D_ + (j)*64]; \
        uint4 w##j##_4 = wb[4*D_ + (j)*64]; uint4 w##j##_5 = wb[5*D_ + (j)*64]; \
        uint4 w##j##_6 = wb[6*D_ + (j)*64]; uint4 w##j##_7 = wb[7*D_ + (j)*64];
    WDEC(0) WDEC(1) WDEC(2) WDEC(3) WDEC(4) WDEC(5)
    #undef WDEC
    #pragma unroll
    for (int c = 0; c < 8; ++c) {
        wl[0][c][tid] = wb[c * D_ + 6 * 64];
        wl[1][c][tid] = wb[c * D_ + 7 * 64];
    }

    if (tid == 0) { flag[0] = -2; flag[1] = -2; }
    float* orow = out + (size_t)b * L_ * D_ + tid;
    __syncthreads();                       // us + wl + flag visible

    const float u_reg = us[tid];

    float hval = 0.f, hprev = 0.f, hprev2 = 0.f;
    int   ts   = count;
    float aval = 0.f, bval = 0.f;

    for (int t = 0; t < count; ++t) {
        // ---- pack h pairs in-register (wave-local; h[64w+L] lives in lane L)
        const float pa = __shfl_xor(hval, 1, 64);
        const unsigned hp = (lane & 1) ? packh(pa, hval) : packh(hval, pa);

        float p0 = 0.f, p1 = 0.f, p2 = 0.f, p3 = 0.f;
        float p4 = 0.f, p5 = 0.f, p6 = 0.f, p7 = 0.f;

        #define STEPC(c) { \
            const unsigned hx = (unsigned)__builtin_amdgcn_readlane((int)hp, 8*(c)+0); \
            const unsigned hy = (unsigned)__builtin_amdgcn_readlane((int)hp, 8*(c)+2); \
            const unsigned hz = (unsigned)__builtin_amdgcn_readlane((int)hp, 8*(c)+4); \
            const unsigned hw = (unsigned)__builtin_amdgcn_readlane((int)hp, 8*(c)+6); \
            p0 = fdot2f(w0_##c.x, hx, p0); p0 = fdot2f(w0_##c.y, hy, p0); \
            p0 = fdot2f(w0_##c.z, hz, p0); p0 = fdot2f(w0_##c.w, hw, p0); \
            p1 = fdot2f(w1_##c.x, hx, p1); p1 = fdot2f(w1_##c.y, hy, p1); \
            p1 = fdot2f(w1_##c.z, hz, p1); p1 = fdot2f(w1_##c.w, hw, p1); \
            p2 = fdot2f(w2_##c.x, hx, p2); p2 = fdot2f(w2_##c.y, hy, p2); \
            p2 = fdot2f(w2_##c.z, hz, p2); p2 = fdot2f(w2_##c.w, hw, p2); \
            p3 = fdot2f(w3_##c.x, hx, p3); p3 = fdot2f(w3_##c.y, hy, p3); \
            p3 = fdot2f(w3_##c.z, hz, p3); p3 = fdot2f(w3_##c.w, hw, p3); \
            p4 = fdot2f(w4_##c.x, hx, p4); p4 = fdot2f(w4_##c.y, hy, p4); \
            p4 = fdot2f(w4_##c.z, hz, p4); p4 = fdot2f(w4_##c.w, hw, p4); \
            p5 = fdot2f(w5_##c.x, hx, p5); p5 = fdot2f(w5_##c.y, hy, p5); \
            p5 = fdot2f(w5_##c.z, hz, p5); p5 = fdot2f(w5_##c.w, hw, p5); \
            uint4 x6 = wl[0][c][tid]; \
            p6 = fdot2f(x6.x, hx, p6); p6 = fdot2f(x6.y, hy, p6); \
            p6 = fdot2f(x6.z, hz, p6); p6 = fdot2f(x6.w, hw, p6); \
            uint4 x7 = wl[1][c][tid]; \
            p7 = fdot2f(x7.x, hx, p7); p7 = fdot2f(x7.y, hy, p7); \
            p7 = fdot2f(x7.z, hz, p7); p7 = fdot2f(x7.w, hw, p7); }
        STEPC(0) STEPC(1) STEPC(2) STEPC(3)
        STEPC(4) STEPC(5) STEPC(6) STEPC(7)
        #undef STEPC

        // partials (f16, RNE) -> pb16[t&1][w][d=lane*8 .. +8) as one b128
        uint4 qv = make_uint4(packh(p0, p1), packh(p2, p3),
                              packh(p4, p5), packh(p6, p7));
        *reinterpret_cast<uint4*>(&pb16[t & 1][w][lane * 8]) = qv;

        lds_barrier();                     // the ONE barrier per step

        // ---- delayed exit check: flags from step t-1 are now visible
        if (t >= 3 && flag[(t - 1) & 1] != t - 1) {
            ts   = t;                      // rows t.. periodic
            aval = hprev;                  // row t   (parity 0)
            bval = hval;                   // row t+1 (parity 1)
            break;
        }

        // ---- reduce output d = tid
        float s = u_reg;
        #pragma unroll
        for (int w2 = 0; w2 < 8; ++w2)
            s += (float)pb16[t & 1][w2][tid];

        const float h = fast_tanh(s);
        orow[(size_t)t * D_] = h;          // fire-and-forget

        const float df = fabsf(h - hprev); // |h_t - h_{t-2}|
        hprev2 = hprev; hprev = hval; hval = h;

        if (t < 2 || df > EPS) flag[t & 1] = t;   // benign same-value race
    }

    hA[b * D_ + tid] = aval;
    hB[b * D_ + tid] = bval;
    if (tid == 0) tstop[b] = ts;
}

// Rows [ts,count): alternate hA/hB by parity of (t-ts). Rows [count,L): zeros.
__global__ __launch_bounds__(256) void fill_kernel(
    const int* __restrict__ counts, const int* __restrict__ tstop,
    const float* __restrict__ hA, const float* __restrict__ hB,
    float* __restrict__ out)
{
    const int b   = blockIdx.y;
    const int c   = blockIdx.x;          // 128 chunks of 16 rows
    const int tid = threadIdx.x;
    const int count = clampc(counts[b]);
    const int ts  = tstop[b];

    const int d4   = tid & 127;
    const int rsub = tid >> 7;           // 0..1
    const float4 av = reinterpret_cast<const float4*>(hA + (size_t)b * D_)[d4];
    const float4 bv = reinterpret_cast<const float4*>(hB + (size_t)b * D_)[d4];
    const float4 z  = make_float4(0.f, 0.f, 0.f, 0.f);
    float4* ob = reinterpret_cast<float4*>(out + (size_t)b * L_ * D_);

    #pragma unroll
    for (int rr = 0; rr < 8; ++rr) {
        const int t = c * 16 + rr * 2 + rsub;
        if (t < ts) continue;
        float4 v = z;
        if (t < count) v = ((t - ts) & 1) ? bv : av;
        ob[(size_t)t * (D_ / 4) + d4] = v;
    }
}

extern "C" void kernel_launch(void* const* d_in, const int* in_sizes, int n_in,
                              void* d_out, int out_size, void* d_ws, size_t ws_size,
                              hipStream_t stream) {
    const int*   counts = (const int*)d_in[0];
    const float* x      = (const float*)d_in[1];
    const float* W_ih   = (const float*)d_in[2];
    const float* W_hh   = (const float*)d_in[3];
    const float* b_ih   = (const float*)d_in[4];
    const float* b_hh   = (const float*)d_in[5];
    float* out = (float*)d_out;

    char* ws = (char*)d_ws;
    uint4* wt8 = (uint4*)ws;                                   // 512 KB
    float* hA  = (float*)(ws + (512 << 10));                   // 128 KB
    float* hB  = (float*)(ws + (640 << 10));                   // 128 KB
    int*   tstop = (int*)(ws + (768 << 10));                   // 256 B

    hipLaunchKernelGGL(prep_kernel, dim3(64), dim3(512), 0, stream,
                       W_hh, wt8);
    hipLaunchKernelGGL(rnn_kernel, dim3(B_), dim3(512), 0, stream,
                       counts, x, W_ih, b_ih, b_hh, wt8, out, hA, hB, tstop);
    hipLaunchKernelGGL(fill_kernel, dim3(128, B_), dim3(256), 0, stream,
                       counts, tstop, hA, hB, out);
}

// Round 16
// 81.442 us; speedup vs baseline: 1.4777x; 1.4777x over previous
//
#include <hip/hip_runtime.h>
#include <hip/hip_bf16.h>
#include <math.h>

#define B_    64
#define L_    2048
#define D_    512
#define EPS   6e-3f   // period-2 exit threshold (R15 showed freeze error < f16 noise)

typedef _Float16 half2v __attribute__((ext_vector_type(2)));

// Packed f16 dot-2 with f32 accumulate (VOP3P v_dot2_f32_f16 via builtin).
__device__ inline float fdot2f(unsigned wu, unsigned hu, float acc) {
    return __builtin_amdgcn_fdot2(__builtin_bit_cast(half2v, wu),
                                  __builtin_bit_cast(half2v, hu), acc, false);
}

__device__ inline float fast_tanh(float x) {
    float e = __expf(2.0f * x);           // inf for large x is fine
    return 1.0f - 2.0f / (e + 1.0f);
}

// LDS-only barrier: waits this wave's LDS ops, then raw s_barrier.
// Does not drain vmcnt — output stores stay in flight across steps.
__device__ inline void lds_barrier() {
    asm volatile("s_waitcnt lgkmcnt(0)" ::: "memory");
    __builtin_amdgcn_s_barrier();
    __builtin_amdgcn_sched_barrier(0);
}

__device__ inline int clampc(int c) { return c < 0 ? 0 : (c > L_ ? L_ : c); }

__device__ inline unsigned packh(float lo, float hi) {
    half2v v; v[0] = (_Float16)lo; v[1] = (_Float16)hi;   // RNE casts
    return __builtin_bit_cast(unsigned, v);
}

// 192 blocks x 512 threads.
// blocks [0,128): u2[h][b][d] = partial of x[b]·W_ih[d] over k in [256h,256h+256)
//                 (+ biases in half 0).
// blocks [128,192): TILED transpose W_hh -> WT8 packed f16 pairs, layout
//   wt8[k8*512 + j*64 + lane] = pack(W_hh[lane*8+j][8k8..8k8+8)).
//   8x8 grid of 64x64 tiles; reads 256B-contiguous, writes 128B-contiguous.
__global__ __launch_bounds__(512) void prep_kernel(
    const float* __restrict__ x, const float* __restrict__ W_ih,
    const float* __restrict__ W_hh, const float* __restrict__ b_ih,
    const float* __restrict__ b_hh, uint4* __restrict__ wt8,
    float* __restrict__ u2)
{
    const int blk = blockIdx.x;
    const int tid = threadIdx.x;
    if (blk < 128) {
        const int h = blk >> 6;            // K-half 0/1
        const int b = blk & 63;            // sample
        __shared__ float xs[256];
        if (tid < 256) xs[tid] = x[b * D_ + h * 256 + tid];
        __syncthreads();
        const float4* wrow = reinterpret_cast<const float4*>(
            W_ih + (size_t)tid * D_ + h * 256);
        const float4* xv = reinterpret_cast<const float4*>(xs);
        float acc = (h == 0) ? (b_ih[tid] + b_hh[tid]) : 0.f;
        #pragma unroll 8
        for (int k = 0; k < 64; ++k) {
            float4 w = wrow[k]; float4 xx = xv[k];
            acc += w.x * xx.x + w.y * xx.y + w.z * xx.z + w.w * xx.w;
        }
        u2[(size_t)h * B_ * D_ + b * D_ + tid] = acc;
    } else {
        const int T  = blk - 128;          // 0..63
        const int gi = T >> 3, gj = T & 7; // tile (row-group, col-group)
        __shared__ unsigned st[64][32];    // 8 KB staged f16-pairs

        // read phase: thread reads 8 consecutive floats of one tile row
        const int r  = tid >> 3;           // 0..63 (row within tile)
        const int c8 = tid & 7;            // 0..7  (8-col group)
        const float* src = W_hh + (size_t)(64 * gi + r) * D_ + 64 * gj + c8 * 8;
        const float4 v0 = reinterpret_cast<const float4*>(src)[0];
        const float4 v1 = reinterpret_cast<const float4*>(src)[1];
        const int cw = ((c8 ^ (r & 7)) << 2);   // XOR swizzle, 4-aligned
        st[r][cw + 0] = packh(v0.x, v0.y);
        st[r][cw + 1] = packh(v0.z, v0.w);
        st[r][cw + 2] = packh(v1.x, v1.y);
        st[r][cw + 3] = packh(v1.z, v1.w);
        __syncthreads();

        // write phase: thread writes one uint4 of wt8, 128B-contiguous per (k8,j)
        const int k8l = tid >> 6;          // 0..7 (k8 within tile)
        const int j   = (tid >> 3) & 7;
        const int l8  = tid & 7;
        const int r2  = l8 * 8 + j;        // row within tile
        const int cr  = ((k8l ^ j) << 2);  // matches staging swizzle
        const uint4 o = *reinterpret_cast<const uint4*>(&st[r2][cr]);
        wt8[(size_t)(8 * gj + k8l) * D_ + j * 64 + 8 * gi + l8] = o;
    }
}

#define REP48(M) M(0)M(1)M(2)M(3)M(4)M(5)M(6)M(7)M(8)M(9)M(10)M(11)M(12)M(13)\
M(14)M(15)M(16)M(17)M(18)M(19)M(20)M(21)M(22)M(23)M(24)M(25)M(26)M(27)M(28)\
M(29)M(30)M(31)M(32)M(33)M(34)M(35)M(36)M(37)M(38)M(39)M(40)M(41)M(42)M(43)\
M(44)M(45)M(46)M(47)

// 64 blocks x 512 threads, K-split across waves; h in registers
// (readlane broadcast); one lds_barrier/step; delayed exit check.
__global__ __launch_bounds__(512, 2) void rnn_kernel(
    const int* __restrict__ counts, const float* __restrict__ u2,
    const uint4* __restrict__ wt8, float* __restrict__ out,
    float* __restrict__ hA, float* __restrict__ hB, int* __restrict__ tstop)
{
    const int b    = blockIdx.x;
    const int tid  = threadIdx.x;
    const int w    = tid >> 6;     // wave 0..7
    const int lane = tid & 63;
    const int w8   = w * 8;        // first owned K-chunk
    const int count = clampc(counts[b]);

    __shared__ __align__(16) uint4 wl[2][8][512];        // 128 KB (j=6,7 tails)
    __shared__ __align__(16) _Float16 pb16[2][8][D_];    // 16 KB partials, dbuf
    __shared__ int flag[2];

    // W loads j=0..5 into named regs (coalesced), j=6,7 into LDS.
    const uint4* wb = wt8 + (size_t)w8 * D_ + lane;
    #define WDEC(j) \
        uint4 w##j##_0 = wb[0*D_ + (j)*64]; uint4 w##j##_1 = wb[1*D_ + (j)*64]; \
        uint4 w##j##_2 = wb[2*D_ + (j)*64]; uint4 w##j##_3 = wb[3*D_ + (j)*64]; \
        uint4 w##j##_4 = wb[4*D_ + (j)*64]; uint4 w##j##_5 = wb[5*D_ + (j)*64]; \
        uint4 w##j##_6 = wb[6*D_ + (j)*64]; uint4 w##j##_7 = wb[7*D_ + (j)*64];
    WDEC(0) WDEC(1) WDEC(2) WDEC(3) WDEC(4) WDEC(5)
    #undef WDEC
    #pragma unroll
    for (int c = 0; c < 8; ++c) {
        wl[0][c][tid] = wb[c * D_ + 6 * 64];
        wl[1][c][tid] = wb[c * D_ + 7 * 64];
    }

    if (tid == 0) { flag[0] = -2; flag[1] = -2; }

    const float u_reg = u2[b * D_ + tid] + u2[B_ * D_ + b * D_ + tid];
    float* orow = out + (size_t)b * L_ * D_ + tid;
    __syncthreads();                       // full drain once (W loads -> LDS)

    float hval = 0.f, hprev = 0.f, hprev2 = 0.f;
    int   ts   = count;
    float aval = 0.f, bval = 0.f;

    for (int t = 0; t < count; ++t) {
        // ---- pack h pairs in-register (wave-local; h[64w+L] lives in lane L)
        const float pa = __shfl_xor(hval, 1, 64);
        const unsigned hp = (lane & 1) ? packh(pa, hval) : packh(hval, pa);

        float p0 = 0.f, p1 = 0.f, p2 = 0.f, p3 = 0.f;
        float p4 = 0.f, p5 = 0.f, p6 = 0.f, p7 = 0.f;

        #define STEPC(c) { \
            const unsigned hx = (unsigned)__builtin_amdgcn_readlane((int)hp, 8*(c)+0); \
            const unsigned hy = (unsigned)__builtin_amdgcn_readlane((int)hp, 8*(c)+2); \
            const unsigned hz = (unsigned)__builtin_amdgcn_readlane((int)hp, 8*(c)+4); \
            const unsigned hw = (unsigned)__builtin_amdgcn_readlane((int)hp, 8*(c)+6); \
            p0 = fdot2f(w0_##c.x, hx, p0); p0 = fdot2f(w0_##c.y, hy, p0); \
            p0 = fdot2f(w0_##c.z, hz, p0); p0 = fdot2f(w0_##c.w, hw, p0); \
            p1 = fdot2f(w1_##c.x, hx, p1); p1 = fdot2f(w1_##c.y, hy, p1); \
            p1 = fdot2f(w1_##c.z, hz, p1); p1 = fdot2f(w1_##c.w, hw, p1); \
            p2 = fdot2f(w2_##c.x, hx, p2); p2 = fdot2f(w2_##c.y, hy, p2); \
            p2 = fdot2f(w2_##c.z, hz, p2); p2 = fdot2f(w2_##c.w, hw, p2); \
            p3 = fdot2f(w3_##c.x, hx, p3); p3 = fdot2f(w3_##c.y, hy, p3); \
            p3 = fdot2f(w3_##c.z, hz, p3); p3 = fdot2f(w3_##c.w, hw, p3); \
            p4 = fdot2f(w4_##c.x, hx, p4); p4 = fdot2f(w4_##c.y, hy, p4); \
            p4 = fdot2f(w4_##c.z, hz, p4); p4 = fdot2f(w4_##c.w, hw, p4); \
            p5 = fdot2f(w5_##c.x, hx, p5); p5 = fdot2f(w5_##c.y, hy, p5); \
            p5 = fdot2f(w5_##c.z, hz, p5); p5 = fdot2f(w5_##c.w, hw, p5); \
            uint4 x6 = wl[0][c][tid]; \
            p6 = fdot2f(x6.x, hx, p6); p6 = fdot2f(x6.y, hy, p6); \
            p6 = fdot2f(x6.z, hz, p6); p6 = fdot2f(x6.w, hw, p6); \
            uint4 x7 = wl[1][c][tid]; \
            p7 = fdot2f(x7.x, hx, p7); p7 = fdot2f(x7.y, hy, p7); \
            p7 = fdot2f(x7.z, hz, p7); p7 = fdot2f(x7.w, hw, p7); }
        STEPC(0) STEPC(1) STEPC(2) STEPC(3)
        STEPC(4) STEPC(5) STEPC(6) STEPC(7)
        #undef STEPC

        // partials (f16, RNE) -> pb16[t&1][w][d=lane*8 .. +8) as one b128
        uint4 qv = make_uint4(packh(p0, p1), packh(p2, p3),
                              packh(p4, p5), packh(p6, p7));
        *reinterpret_cast<uint4*>(&pb16[t & 1][w][lane * 8]) = qv;

        lds_barrier();                     // the ONE barrier per step

        // ---- delayed exit check: flags from step t-1 are now visible
        if (t >= 3 && flag[(t - 1) & 1] != t - 1) {
            ts   = t;                      // rows t.. periodic
            aval = hprev;                  // row t   (parity 0)
            bval = hval;                   // row t+1 (parity 1)
            break;
        }

        // ---- reduce output d = tid
        float s = u_reg;
        #pragma unroll
        for (int w2 = 0; w2 < 8; ++w2)
            s += (float)pb16[t & 1][w2][tid];

        const float h = fast_tanh(s);
        orow[(size_t)t * D_] = h;          // fire-and-forget

        const float df = fabsf(h - hprev); // |h_t - h_{t-2}|
        hprev2 = hprev; hprev = hval; hval = h;

        if (t < 2 || df > EPS) flag[t & 1] = t;   // benign same-value race
    }

    hA[b * D_ + tid] = aval;
    hB[b * D_ + tid] = bval;
    if (tid == 0) tstop[b] = ts;
}

// Rows [ts,count): alternate hA/hB by parity of (t-ts). Rows [count,L): zeros.
__global__ __launch_bounds__(256) void fill_kernel(
    const int* __restrict__ counts, const int* __restrict__ tstop,
    const float* __restrict__ hA, const float* __restrict__ hB,
    float* __restrict__ out)
{
    const int b   = blockIdx.y;
    const int c   = blockIdx.x;          // 128 chunks of 16 rows
    const int tid = threadIdx.x;
    const int count = clampc(counts[b]);
    const int ts  = tstop[b];

    const int d4   = tid & 127;
    const int rsub = tid >> 7;           // 0..1
    const float4 av = reinterpret_cast<const float4*>(hA + (size_t)b * D_)[d4];
    const float4 bv = reinterpret_cast<const float4*>(hB + (size_t)b * D_)[d4];
    const float4 z  = make_float4(0.f, 0.f, 0.f, 0.f);
    float4* ob = reinterpret_cast<float4*>(out + (size_t)b * L_ * D_);

    #pragma unroll
    for (int rr = 0; rr < 8; ++rr) {
        const int t = c * 16 + rr * 2 + rsub;
        if (t < ts) continue;
        float4 v = z;
        if (t < count) v = ((t - ts) & 1) ? bv : av;
        ob[(size_t)t * (D_ / 4) + d4] = v;
    }
}

extern "C" void kernel_launch(void* const* d_in, const int* in_sizes, int n_in,
                              void* d_out, int out_size, void* d_ws, size_t ws_size,
                              hipStream_t stream) {
    const int*   counts = (const int*)d_in[0];
    const float* x      = (const float*)d_in[1];
    const float* W_ih   = (const float*)d_in[2];
    const float* W_hh   = (const float*)d_in[3];
    const float* b_ih   = (const float*)d_in[4];
    const float* b_hh   = (const float*)d_in[5];
    float* out = (float*)d_out;

    char* ws = (char*)d_ws;
    uint4* wt8 = (uint4*)ws;                                   // 512 KB
    float* u2  = (float*)(ws + (512 << 10));                   // 256 KB (2 halves)
    float* hA  = (float*)(ws + (768 << 10));                   // 128 KB
    float* hB  = (float*)(ws + (896 << 10));                   // 128 KB
    int*   tstop = (int*)(ws + (1024 << 10));                  // 256 B

    hipLaunchKernelGGL(prep_kernel, dim3(192), dim3(512), 0, stream,
                       x, W_ih, W_hh, b_ih, b_hh, wt8, u2);
    hipLaunchKernelGGL(rnn_kernel, dim3(B_), dim3(512), 0, stream,
                       counts, u2, wt8, out, hA, hB, tstop);
    hipLaunchKernelGGL(fill_kernel, dim3(128, B_), dim3(256), 0, stream,
                       counts, tstop, hA, hB, out);
}